// Round 4
// baseline (1953.902 us; speedup 1.0000x reference)
//
#include <hip/hip_runtime.h>
#include <hip/hip_bf16.h>

#define NTOK  49
#define CDIM  256
#define NHD   8
#define HDIM  32
#define HP    224
#define WPW   224
#define SHIFT 3

typedef __attribute__((ext_vector_type(8))) short short8;
typedef __attribute__((ext_vector_type(4))) short short4v;
typedef __attribute__((ext_vector_type(4))) float float4v;

static __device__ __forceinline__ short f2bf(float f) {
    unsigned u = __float_as_uint(f);
    u += 0x7FFF + ((u >> 16) & 1);          // round-to-nearest-even
    return (short)(u >> 16);
}

// ---------- pre-kernel: qkv_w fp32 -> bf16 row-major in workspace ----------
__global__ void cvt_w_kernel(const float* __restrict__ w, short* __restrict__ wb) {
    int t = blockIdx.x * 256 + threadIdx.x;     // 49152 threads, 4 elems each
    float4v f = *(const float4v*)(w + (size_t)t * 4);
    short4v o;
    o.x = f2bf(f.x); o.y = f2bf(f.y); o.z = f2bf(f.z); o.w = f2bf(f.w);
    *(short4v*)(wb + (size_t)t * 4) = o;
}

// ---------- fused swin attention ----------
// LDS: xs bf16 [8 kt][49 m][40]  (A-fragments: ds_read_b128, 80B row stride)
//      q/k/v fp32 [49][36], attn fp32 [49][50], nsrc[49], btab_h[169]
struct SM {
    short xs[8 * 49 * 40];     // 31360 B
    float q[49 * 36];          // 7056 B
    float k[49 * 36];
    float v[49 * 36];
    float attn[49 * 50];       // 9800 B
    float btab_h[169];         //  676 B  rel-bias slice for current head
    int   nsrc[49];
};                             // total 63200 B -> 2 blocks/CU

__global__ __launch_bounds__(256, 2)
void swin_attn_kernel(const float* __restrict__ x,
                      const float* __restrict__ mask,
                      const float* __restrict__ qkv_b,
                      const float* __restrict__ btab,
                      const short* __restrict__ wb,
                      float* __restrict__ out)
{
    __shared__ __align__(16) SM S;

    const int tid = threadIdx.x;
    const int blk = blockIdx.x;
    const int b   = blk >> 10;
    const int wi  = blk & 1023;
    const int wh  = wi >> 5, ww = wi & 31;

    if (tid < NTOK) {
        int i = tid / 7, j = tid - i * 7;
        int hs = wh * 7 + i + SHIFT;  if (hs >= HP)  hs -= HP;
        int wsx = ww * 7 + j + SHIFT; if (wsx >= WPW) wsx -= WPW;
        S.nsrc[tid] = hs * WPW + wsx;
    }
    __syncthreads();

    // ---- stage x window as bf16 A-fragments ----
    const size_t xbase = (size_t)b * (HP * WPW) * CDIM;
    for (int idx = tid; idx < NTOK * 64; idx += 256) {
        int r = idx >> 6, k4 = idx & 63;
        float4v f = *(const float4v*)(x + xbase + (size_t)S.nsrc[r] * CDIM + k4 * 4);
        short4v o;
        o.x = f2bf(f.x); o.y = f2bf(f.y); o.z = f2bf(f.z); o.w = f2bf(f.w);
        int kt = k4 >> 3, kk = (k4 & 7) * 4;
        *(short4v*)&S.xs[(kt * 49 + r) * 40 + kk] = o;
    }
    __syncthreads();

    const int lane = tid & 63;
    const int w    = tid >> 6;
    const int n16  = lane & 15;
    const int quad = lane >> 4;
    const int m16  = lane & 15;

    // wave -> N-tile assignment: w0:{0,1} w1:{2,3} w2:{4} w3:{5}
    const int ncnt = (w < 2) ? 2 : 1;
    const int ntb  = (w < 2) ? 2 * w : w + 2;

    const float scale = 0.17677669529663687f;   // 1/sqrt(32)
    const float* maskp = mask + (size_t)wi * 2401;

    for (int h = 0; h < NHD; ++h) {
        // ---- QKV GEMM for head h: [64x256] @ [256x96] via MFMA ----
        int   seg[2], colb[2];
        const short* bptr[2];
        float bias[2];
        for (int i = 0; i < ncnt; ++i) {
            int j0 = (ntb + i) * 16;
            seg[i]  = j0 >> 5;
            colb[i] = j0 & 31;
            int chan = seg[i] * 256 + h * 32 + colb[i] + n16;
            bptr[i] = wb + (size_t)chan * 256 + quad * 8;
            bias[i] = qkv_b[chan];
        }

        float4v acc[4][2];
#pragma unroll
        for (int mt = 0; mt < 4; ++mt)
            for (int i = 0; i < 2; ++i)
                acc[mt][i] = (float4v)0.0f;

        for (int kt = 0; kt < 8; ++kt) {
            short8 a[4];
#pragma unroll
            for (int mt = 0; mt < 4; ++mt)
                a[mt] = *(const short8*)&S.xs[(kt * 49 + mt * 16 + m16) * 40 + quad * 8];
            for (int i = 0; i < ncnt; ++i) {
                short8 bf = *(const short8*)(bptr[i] + kt * 32);
#pragma unroll
                for (int mt = 0; mt < 4; ++mt)
                    acc[mt][i] = __builtin_amdgcn_mfma_f32_16x16x32_bf16(a[mt], bf, acc[mt][i], 0, 0, 0);
            }
        }

        // stage this head's rel-bias slice while QKV epilogue runs
        if (tid < 169) S.btab_h[tid] = btab[tid * 8 + h];

        // epilogue: D[r][c] -> q/k/v LDS (+bias); r = mt*16 + quad*4 + reg
        for (int i = 0; i < ncnt; ++i) {
            float* dst = (seg[i] == 0) ? S.q : (seg[i] == 1) ? S.k : S.v;
            int col = colb[i] + n16;
#pragma unroll
            for (int mt = 0; mt < 4; ++mt) {
#pragma unroll
                for (int reg = 0; reg < 4; ++reg) {
                    int r = mt * 16 + quad * 4 + reg;
                    if (r < NTOK) dst[r * 36 + col] = acc[mt][i][reg] + bias[i];
                }
            }
        }
        __syncthreads();

        // ---- logits: 4-row register tiling, float4 LDS reads ----
        for (int u = tid; u < 13 * 49; u += 256) {
            int rg = u / 49, c = u - rg * 49;
            int r0 = rg * 4;
            int nr = (r0 + 4 <= NTOK) ? 4 : (NTOK - r0);
            float4v kf[8];
#pragma unroll
            for (int d = 0; d < 8; ++d)
                kf[d] = *(const float4v*)&S.k[c * 36 + d * 4];
            int i2 = c / 7, j2 = c - i2 * 7;
            for (int rr = 0; rr < nr; ++rr) {
                int r = r0 + rr;
                float4v s = (float4v)0.0f;
#pragma unroll
                for (int d = 0; d < 8; ++d) {
                    float4v qv = *(const float4v*)&S.q[r * 36 + d * 4];
                    s += qv * kf[d];
                }
                int i1 = r / 7, j1 = r - i1 * 7;
                int bidx = (i1 - i2 + 6) * 13 + (j1 - j2 + 6);
                S.attn[r * 50 + c] = (s.x + s.y + s.z + s.w) * scale
                                   + S.btab_h[bidx]
                                   + maskp[r * 49 + c];
            }
        }
        __syncthreads();

        // ---- softmax: 4 lanes per row (groups of 4 never cross a wave) ----
        if (tid < 196) {
            int r = tid >> 2, sx = tid & 3;
            float* row = &S.attn[r * 50];
            float mx = -1e30f;
            for (int c = sx; c < NTOK; c += 4) mx = fmaxf(mx, row[c]);
            mx = fmaxf(mx, __shfl_xor(mx, 1));
            mx = fmaxf(mx, __shfl_xor(mx, 2));
            float sum = 0.f;
            for (int c = sx; c < NTOK; c += 4) {
                float e = __expf(row[c] - mx);
                row[c] = e; sum += e;
            }
            sum += __shfl_xor(sum, 1);
            sum += __shfl_xor(sum, 2);
            float inv = 1.0f / sum;
            for (int c = sx; c < NTOK; c += 4) row[c] *= inv;
        }
        __syncthreads();

        // ---- out = attn @ v : 2 rows x 4 dims per thread ----
        if (tid < 200) {
            int rg2 = tid >> 3, d4 = tid & 7;
            int r0 = rg2 * 2, r1 = r0 + 1;
            bool has1 = (r1 < NTOK);
            float4v o0 = (float4v)0.0f, o1 = (float4v)0.0f;
            for (int c = 0; c < NTOK; ++c) {
                float4v vv = *(const float4v*)&S.v[c * 36 + d4 * 4];
                float a0 = S.attn[r0 * 50 + c];
                o0 += a0 * vv;
                if (has1) {
                    float a1 = S.attn[r1 * 50 + c];
                    o1 += a1 * vv;
                }
            }
            *(float4v*)(out + xbase + (size_t)S.nsrc[r0] * CDIM + h * HDIM + d4 * 4) = o0;
            if (has1)
                *(float4v*)(out + xbase + (size_t)S.nsrc[r1] * CDIM + h * HDIM + d4 * 4) = o1;
        }
        __syncthreads();
    }
}

extern "C" void kernel_launch(void* const* d_in, const int* in_sizes, int n_in,
                              void* d_out, int out_size, void* d_ws, size_t ws_size,
                              hipStream_t stream) {
    const float* x      = (const float*)d_in[0];
    const float* mask   = (const float*)d_in[1];
    const float* qkv_w  = (const float*)d_in[2];
    const float* qkv_b  = (const float*)d_in[3];
    const float* btab   = (const float*)d_in[4];
    float* out = (float*)d_out;
    short* wb  = (short*)d_ws;                 // 768*256 bf16 = 384 KB

    cvt_w_kernel<<<dim3(192), dim3(256), 0, stream>>>(qkv_w, wb);
    swin_attn_kernel<<<dim3(4096), dim3(256), 0, stream>>>(
        x, mask, qkv_b, btab, wb, out);
}

// Round 5
// 950.058 us; speedup vs baseline: 2.0566x; 2.0566x over previous
//
#include <hip/hip_runtime.h>
#include <hip/hip_bf16.h>

#define NTOK  49
#define CDIM  256
#define NHD   8
#define HDIM  32
#define HP    224
#define WPW   224
#define SHIFT 3

typedef __attribute__((ext_vector_type(8))) short short8;
typedef __attribute__((ext_vector_type(4))) short short4v;
typedef __attribute__((ext_vector_type(4))) float float4v;

static __device__ __forceinline__ short f2bf(float f) {
    unsigned u = __float_as_uint(f);
    u += 0x7FFF + ((u >> 16) & 1);          // round-to-nearest-even
    return (short)(u >> 16);
}

// ---------- pre-kernel: qkv_w fp32 -> bf16 row-major in workspace ----------
__global__ void cvt_w_kernel(const float* __restrict__ w, short* __restrict__ wb) {
    int t = blockIdx.x * 256 + threadIdx.x;     // 49152 threads, 4 elems each
    float4v f = *(const float4v*)(w + (size_t)t * 4);
    short4v o;
    o.x = f2bf(f.x); o.y = f2bf(f.y); o.z = f2bf(f.z); o.w = f2bf(f.w);
    *(short4v*)(wb + (size_t)t * 4) = o;
}

// ---------- LDS layout: 61952 B total ----------
struct __align__(16) SMem {
    int   nsrc[64];            //   256 B  shifted source token index
    short xs[8 * 49 * 40];     // 31360 B  x window as bf16 A-fragments
    float btabt[8 * 169];      //  5408 B  rel-bias TRANSPOSED [h][169]
    float pad_[8];             //    32 B  (16B-align wv)
    struct {
        union {
            struct { short q[49 * 40]; short k[49 * 40]; } qk;  // 7840 B
            short p[64 * 40];                                   // 5120 B (per-chunk)
            float o[49 * 36];                                   // 7056 B
        } r1;                  // 7840 B
        short vT[32 * 72];     // 4608 B  V transposed [dim][token], cols 49..63 zeroed
    } wv[2];                   // per-wave scratch
};

__global__ __launch_bounds__(128, 1)
void swin_attn_kernel(const float* __restrict__ x,
                      const float* __restrict__ mask,
                      const float* __restrict__ qkv_b,
                      const float* __restrict__ btab,
                      const short* __restrict__ wb,
                      float* __restrict__ out)
{
    __shared__ SMem S;

    const int tid = threadIdx.x;
    const int blk = blockIdx.x;
    const int b   = blk >> 10;
    const int wi  = blk & 1023;
    const int wh  = wi >> 5, ww = wi & 31;

    if (tid < NTOK) {
        int i = tid / 7, j = tid - i * 7;
        int hs = wh * 7 + i + SHIFT;  if (hs >= HP)  hs -= HP;
        int wsx = ww * 7 + j + SHIFT; if (wsx >= WPW) wsx -= WPW;
        S.nsrc[tid] = hs * WPW + wsx;
    }
    // zero both vT buffers once: token-cols 49..63 must be 0 (NaN containment in PV)
    for (int idx = tid; idx < 1152; idx += 128) {
        ((int*)S.wv[0].vT)[idx] = 0;
        ((int*)S.wv[1].vT)[idx] = 0;
    }
    __syncthreads();

    // ---- stage x window as bf16 A-fragments ----
    const size_t xbase = (size_t)b * (HP * WPW) * CDIM;
    for (int idx = tid; idx < NTOK * 64; idx += 128) {
        int r = idx >> 6, k4 = idx & 63;
        float4v f = *(const float4v*)(x + xbase + (size_t)S.nsrc[r] * CDIM + k4 * 4);
        short4v o4;
        o4.x = f2bf(f.x); o4.y = f2bf(f.y); o4.z = f2bf(f.z); o4.w = f2bf(f.w);
        int kt = k4 >> 3, kk = (k4 & 7) * 4;
        *(short4v*)&S.xs[(kt * 49 + r) * 40 + kk] = o4;
    }
    // ---- stage rel-bias table TRANSPOSED: [h][169] ----
    for (int idx = tid; idx < 1352; idx += 128) {
        int h2 = idx & 7, bi = idx >> 3;
        S.btabt[h2 * 169 + bi] = btab[idx];
    }
    __syncthreads();

    const int lane = tid & 63;
    const int w    = tid >> 6;
    const int n16  = lane & 15;
    const int quad = lane >> 4;
    const float scale = 0.17677669529663687f;   // 1/sqrt(32)

    auto& W = S.wv[w];

    // per-lane relative-position terms: bidx = rt[mt][reg] - ct[nt]
    int rt[4][4], ct[4];
#pragma unroll
    for (int mt = 0; mt < 4; ++mt)
#pragma unroll
        for (int reg = 0; reg < 4; ++reg) {
            int r = mt * 16 + quad * 4 + reg;
            int i1 = r / 7;
            rt[mt][reg] = i1 * 13 + (r - i1 * 7);
        }
#pragma unroll
    for (int nt = 0; nt < 4; ++nt) {
        int c = nt * 16 + n16;
        int i2 = c / 7;
        ct[nt] = i2 * 13 + (c - i2 * 7) - 84;
    }

    // window mask into registers once per wave (shared by its 4 heads)
    float mreg[4][4][4];
    {
        const float* maskp = mask + (size_t)wi * 2401;
#pragma unroll
        for (int mt = 0; mt < 4; ++mt)
#pragma unroll
            for (int reg = 0; reg < 4; ++reg) {
                int r  = mt * 16 + quad * 4 + reg;
                int rm = (r < NTOK) ? r : (NTOK - 1);
#pragma unroll
                for (int nt = 0; nt < 4; ++nt) {
                    int c  = nt * 16 + n16;
                    int cm = (c < NTOK) ? c : (NTOK - 1);
                    mreg[mt][nt][reg] = maskp[rm * 49 + cm];
                }
            }
    }

#pragma unroll 1
    for (int h = w * 4; h < w * 4 + 4; ++h) {
        // ---- QKV GEMM for head h: [64x256] @ [256x96] via MFMA ----
        const short* bp[6];
        float bias[6];
#pragma unroll
        for (int i = 0; i < 6; ++i) {
            int chan = (i >> 1) * 256 + h * 32 + (i & 1) * 16 + n16;
            bp[i]   = wb + (size_t)chan * 256 + quad * 8;
            bias[i] = qkv_b[chan];
        }
        float4v acc[4][6];
#pragma unroll
        for (int mt = 0; mt < 4; ++mt)
#pragma unroll
            for (int i = 0; i < 6; ++i)
                acc[mt][i] = (float4v)0.0f;

#pragma unroll
        for (int kt = 0; kt < 8; ++kt) {
            short8 a[4];
#pragma unroll
            for (int mt = 0; mt < 4; ++mt)
                a[mt] = *(const short8*)&S.xs[(kt * 49 + mt * 16 + n16) * 40 + quad * 8];
#pragma unroll
            for (int i = 0; i < 6; ++i) {
                short8 bb = *(const short8*)(bp[i] + kt * 32);
#pragma unroll
                for (int mt = 0; mt < 4; ++mt)
                    acc[mt][i] = __builtin_amdgcn_mfma_f32_16x16x32_bf16(a[mt], bb, acc[mt][i], 0, 0, 0);
            }
        }

        // ---- epilogue: q (scaled), k row-major bf16; v transposed bf16 ----
#pragma unroll
        for (int mt = 0; mt < 4; ++mt)
#pragma unroll
            for (int reg = 0; reg < 4; ++reg) {
                int r = mt * 16 + quad * 4 + reg;
                if (r < NTOK) {
#pragma unroll
                    for (int i = 0; i < 6; ++i) {
                        float v = acc[mt][i][reg] + bias[i];
                        int c = (i & 1) * 16 + n16;
                        if ((i >> 1) == 0)      W.r1.qk.q[r * 40 + c] = f2bf(v * scale);
                        else if ((i >> 1) == 1) W.r1.qk.k[r * 40 + c] = f2bf(v);
                        else                    W.vT[c * 72 + r]      = f2bf(v);
                    }
                }
            }
        __syncthreads();                        // (a) q/k/vT visible

        // ---- QK^T: 16 MFMA, K=32 ----
        short8 aq[4], bk[4];
#pragma unroll
        for (int t = 0; t < 4; ++t) {
            aq[t] = *(const short8*)&W.r1.qk.q[(t * 16 + n16) * 40 + quad * 8];
            bk[t] = *(const short8*)&W.r1.qk.k[(t * 16 + n16) * 40 + quad * 8];
        }
        float4v sa[4][4];
#pragma unroll
        for (int mt = 0; mt < 4; ++mt)
#pragma unroll
            for (int nt = 0; nt < 4; ++nt)
                sa[mt][nt] = __builtin_amdgcn_mfma_f32_16x16x32_bf16(aq[mt], bk[nt], (float4v)0.0f, 0, 0, 0);

        // ---- + rel-bias + mask; cols >= 49 forced to -1e30 ----
        const float* bt = &S.btabt[h * 169];
#pragma unroll
        for (int mt = 0; mt < 4; ++mt)
#pragma unroll
            for (int nt = 0; nt < 4; ++nt)
#pragma unroll
                for (int reg = 0; reg < 4; ++reg) {
                    float sv;
                    if (nt == 3 && n16 >= 1) sv = -1e30f;           // c >= 49
                    else {
                        int bidx = rt[mt][reg] - ct[nt];
                        bidx = (bidx > 168) ? 168 : bidx;           // padding rows: deterministic
                        sv = sa[mt][nt][reg] + bt[bidx] + mreg[mt][nt][reg];
                    }
                    sa[mt][nt][reg] = sv;
                }

        // ---- wave-parallel softmax: row lives across 16 lanes x 4 nt ----
#pragma unroll
        for (int mt = 0; mt < 4; ++mt)
#pragma unroll
            for (int reg = 0; reg < 4; ++reg) {
                float m0 = fmaxf(fmaxf(sa[mt][0][reg], sa[mt][1][reg]),
                                 fmaxf(sa[mt][2][reg], sa[mt][3][reg]));
#pragma unroll
                for (int d = 1; d < 16; d <<= 1) m0 = fmaxf(m0, __shfl_xor(m0, d));
                float s0 = 0.f;
#pragma unroll
                for (int nt = 0; nt < 4; ++nt) {
                    float e = __expf(sa[mt][nt][reg] - m0);
                    sa[mt][nt][reg] = e;
                    s0 += e;
                }
#pragma unroll
                for (int d = 1; d < 16; d <<= 1) s0 += __shfl_xor(s0, d);
                float inv = 1.0f / s0;
#pragma unroll
                for (int nt = 0; nt < 4; ++nt) sa[mt][nt][reg] *= inv;
            }

        // ---- P chunk 0 (k-cols 0..31) -> LDS (overlays dead q/k) ----
#pragma unroll
        for (int mt = 0; mt < 4; ++mt)
#pragma unroll
            for (int reg = 0; reg < 4; ++reg) {
                int q = mt * 16 + quad * 4 + reg;
                W.r1.p[q * 40 + n16]      = f2bf(sa[mt][0][reg]);
                W.r1.p[q * 40 + 16 + n16] = f2bf(sa[mt][1][reg]);
            }
        __syncthreads();                        // (b) p chunk0 visible

        // ---- PV (transposed): D[dim][tok] = V^T @ P^T ----
        float4v oa[2][4];
#pragma unroll
        for (int mtv = 0; mtv < 2; ++mtv)
#pragma unroll
            for (int nt = 0; nt < 4; ++nt)
                oa[mtv][nt] = (float4v)0.0f;

        {   // k-chunk 0 (tokens 0..31)
            short8 av[2], bpv[4];
#pragma unroll
            for (int mtv = 0; mtv < 2; ++mtv)
                av[mtv] = *(const short8*)&W.vT[(mtv * 16 + n16) * 72 + quad * 8];
#pragma unroll
            for (int nt = 0; nt < 4; ++nt)
                bpv[nt] = *(const short8*)&W.r1.p[(nt * 16 + n16) * 40 + quad * 8];
#pragma unroll
            for (int mtv = 0; mtv < 2; ++mtv)
#pragma unroll
                for (int nt = 0; nt < 4; ++nt)
                    oa[mtv][nt] = __builtin_amdgcn_mfma_f32_16x16x32_bf16(av[mtv], bpv[nt], oa[mtv][nt], 0, 0, 0);
        }
        __syncthreads();                        // (c) chunk0 reads done

        // overwrite P with chunk 1 (k-cols 32..63)
#pragma unroll
        for (int mt = 0; mt < 4; ++mt)
#pragma unroll
            for (int reg = 0; reg < 4; ++reg) {
                int q = mt * 16 + quad * 4 + reg;
                W.r1.p[q * 40 + n16]      = f2bf(sa[mt][2][reg]);
                W.r1.p[q * 40 + 16 + n16] = f2bf(sa[mt][3][reg]);
            }
        __syncthreads();                        // (d) p chunk1 visible

        {   // k-chunk 1 (tokens 32..63; vT cols 49..63 are zero)
            short8 av[2], bpv[4];
#pragma unroll
            for (int mtv = 0; mtv < 2; ++mtv)
                av[mtv] = *(const short8*)&W.vT[(mtv * 16 + n16) * 72 + 32 + quad * 8];
#pragma unroll
            for (int nt = 0; nt < 4; ++nt)
                bpv[nt] = *(const short8*)&W.r1.p[(nt * 16 + n16) * 40 + quad * 8];
#pragma unroll
            for (int mtv = 0; mtv < 2; ++mtv)
#pragma unroll
                for (int nt = 0; nt < 4; ++nt)
                    oa[mtv][nt] = __builtin_amdgcn_mfma_f32_16x16x32_bf16(av[mtv], bpv[nt], oa[mtv][nt], 0, 0, 0);
        }
        __syncthreads();                        // (e) chunk1 reads done

        // ---- o -> LDS (overlays dead P), then coalesced 128B stores ----
#pragma unroll
        for (int mtv = 0; mtv < 2; ++mtv)
#pragma unroll
            for (int nt = 0; nt < 4; ++nt)
#pragma unroll
                for (int reg = 0; reg < 4; ++reg) {
                    int qv = nt * 16 + n16;
                    if (qv < NTOK)
                        W.r1.o[qv * 36 + mtv * 16 + quad * 4 + reg] = oa[mtv][nt][reg];
                }
        __syncthreads();                        // (f) o visible
#pragma unroll
        for (int it = 0; it < 7; ++it) {
            int idx = it * 64 + lane;
            if (idx < NTOK * 8) {
                int tok = idx >> 3, c8 = idx & 7;
                float4v ov = *(const float4v*)&W.r1.o[tok * 36 + c8 * 4];
                *(float4v*)(out + xbase + (size_t)S.nsrc[tok] * CDIM + h * HDIM + c8 * 4) = ov;
            }
        }
        __syncthreads();                        // (g) o reads done before next overwrite
    }
}

extern "C" void kernel_launch(void* const* d_in, const int* in_sizes, int n_in,
                              void* d_out, int out_size, void* d_ws, size_t ws_size,
                              hipStream_t stream) {
    const float* x      = (const float*)d_in[0];
    const float* mask   = (const float*)d_in[1];
    const float* qkv_w  = (const float*)d_in[2];
    const float* qkv_b  = (const float*)d_in[3];
    const float* btab   = (const float*)d_in[4];
    float* out = (float*)d_out;
    short* wb  = (short*)d_ws;                 // 768*256 bf16 = 384 KB

    cvt_w_kernel<<<dim3(192), dim3(256), 0, stream>>>(qkv_w, wb);
    swin_attn_kernel<<<dim3(4096), dim3(128), 0, stream>>>(
        x, mask, qkv_b, btab, wb, out);
}

// Round 6
// 847.486 us; speedup vs baseline: 2.3055x; 1.1210x over previous
//
#include <hip/hip_runtime.h>
#include <hip/hip_bf16.h>

#define NTOK  49
#define CDIM  256
#define NHD   8
#define HDIM  32
#define HP    224
#define WPW   224
#define SHIFT 3

typedef __attribute__((ext_vector_type(8))) short short8;
typedef __attribute__((ext_vector_type(4))) short short4v;
typedef __attribute__((ext_vector_type(4))) float float4v;

// zero-cost compiler memory fence: blocks reordering of LDS ops across
// union-overlay transitions; HW LDS pipe is in-order within a wave.
#define MEMFENCE asm volatile("" ::: "memory")

static __device__ __forceinline__ short f2bf(float f) {
    unsigned u = __float_as_uint(f);
    u += 0x7FFF + ((u >> 16) & 1);          // round-to-nearest-even
    return (short)(u >> 16);
}
static __device__ __forceinline__ float bf2f(unsigned short s) {
    return __uint_as_float((unsigned)s << 16);
}

// ---------- pre-kernel: qkv_w fp32 -> bf16 row-major in workspace ----------
__global__ void cvt_w_kernel(const float* __restrict__ w, short* __restrict__ wb) {
    int t = blockIdx.x * 256 + threadIdx.x;     // 49152 threads, 4 elems each
    float4v f = *(const float4v*)(w + (size_t)t * 4);
    short4v o;
    o.x = f2bf(f.x); o.y = f2bf(f.y); o.z = f2bf(f.z); o.w = f2bf(f.w);
    *(short4v*)(wb + (size_t)t * 4) = o;
}

// ---------- LDS layout: 53648 B -> 3 blocks/CU ----------
struct __align__(16) SMem {
    int   nsrc[64];                 //   256 B
    short xs[8 * 49 * 32];          // 25088 B  x window bf16, XOR-swizzled 16B units
    unsigned short btabt[8 * 169];  //  2704 B  rel-bias bf16, transposed [h][169]
    struct WV {
        union {
            struct { short q[49 * 40]; short k[49 * 40]; } qk;  // 7840 B (sigma-permuted cols)
            short p[64 * 64];                                   // 8192 B P^T [q][k], swizzled
            float o[49 * 36];                                   // 7056 B
        } r1;                       // 8192 B
        short vT[32 * 72];          // 4608 B  V^T [dim][token], cols 49..63 zeroed
    } wv[2];                        // 25600 B
};

__global__ __launch_bounds__(128, 1)
void swin_attn_kernel(const float* __restrict__ x,
                      const float* __restrict__ mask,
                      const float* __restrict__ qkv_b,
                      const float* __restrict__ btab,
                      const short* __restrict__ wb,
                      float* __restrict__ out)
{
    __shared__ SMem S;

    const int tid = threadIdx.x;
    const int blk = blockIdx.x;
    const int b   = blk >> 10;
    const int wi  = blk & 1023;
    const int wh  = wi >> 5, ww = wi & 31;

    const int lane = tid & 63;
    const int w    = tid >> 6;
    SMem::WV& W = S.wv[w];

    if (tid < NTOK) {
        int i = tid / 7, j = tid - i * 7;
        int hs = wh * 7 + i + SHIFT;  if (hs >= HP)  hs -= HP;
        int wsx = ww * 7 + j + SHIFT; if (wsx >= WPW) wsx -= WPW;
        S.nsrc[tid] = hs * WPW + wsx;
    }
    // zero own wave's vT once (cols 49..63 must stay 0: NaN containment in PV)
    for (int i2 = lane; i2 < 1152; i2 += 64) ((int*)W.vT)[i2] = 0;
    __syncthreads();

    // ---- stage x window as bf16, swizzled ----
    const size_t xbase = (size_t)b * (HP * WPW) * CDIM;
    for (int idx = tid; idx < NTOK * 64; idx += 128) {
        int r = idx >> 6, k4 = idx & 63;
        float4v f = *(const float4v*)(x + xbase + (size_t)S.nsrc[r] * CDIM + k4 * 4);
        short4v o4;
        o4.x = f2bf(f.x); o4.y = f2bf(f.y); o4.z = f2bf(f.z); o4.w = f2bf(f.w);
        int kt = k4 >> 3;
        int iu = ((k4 >> 1) & 3) ^ ((r >> 1) & 3) ^ ((kt >> 1) & 3);
        *(short4v*)&S.xs[((kt * 49 + r) << 5) + (iu << 3) + ((k4 & 1) << 2)] = o4;
    }
    // ---- stage rel-bias bf16 transposed [h][169] ----
    for (int idx = tid; idx < 1352; idx += 128) {
        int h2 = idx & 7, bi = idx >> 3;
        S.btabt[h2 * 169 + bi] = (unsigned short)f2bf(btab[idx]);
    }
    __syncthreads();
    // ---- no block-wide barriers below: waves fully independent ----

    const int n16  = lane & 15;
    const int quad = lane >> 4;
    const int rs   = (n16 >> 1) & 3;
    const float scale = 0.17677669529663687f;   // 1/sqrt(32)

    // geometry: qv per query-tile ct (query = ct*16+n16); kv per (rt,reg) (key = rt*16+quad*4+reg)
    int qv[4], kv[4][4];
#pragma unroll
    for (int ct = 0; ct < 4; ++ct) {
        int qq = ct * 16 + n16;
        int qi = qq / 7;
        qv[ct] = qi * 13 + (qq - qi * 7);
    }
#pragma unroll
    for (int rt = 0; rt < 4; ++rt)
#pragma unroll
        for (int reg = 0; reg < 4; ++reg) {
            int kk = rt * 16 + quad * 4 + reg;
            int ki = kk / 7;
            kv[rt][reg] = ki * 13 + (kk - ki * 7);
        }

    // window mask into registers (shared by the wave's 4 heads): mask[q][k]
    float mreg[4][4][4];    // [rt][ct][reg]
    {
        const float* maskp = mask + (size_t)wi * 2401;
#pragma unroll
        for (int rt = 0; rt < 4; ++rt)
#pragma unroll
            for (int reg = 0; reg < 4; ++reg) {
                int kk = rt * 16 + quad * 4 + reg;
                int km = (kk < NTOK) ? kk : (NTOK - 1);
#pragma unroll
                for (int ct = 0; ct < 4; ++ct) {
                    int qq = ct * 16 + n16;
                    int qm = (qq < NTOK) ? qq : (NTOK - 1);
                    mreg[rt][ct][reg] = maskp[qm * 49 + km];
                }
            }
    }

#pragma unroll 1
    for (int h = w * 4; h < w * 4 + 4; ++h) {
        // ---- QKV GEMM for head h: [64x256] @ [256x96] via MFMA ----
        const short* bp[6];
        float bias[6];
#pragma unroll
        for (int i = 0; i < 6; ++i) {
            int chan = (i >> 1) * 256 + h * 32 + (i & 1) * 16 + n16;
            bp[i]   = wb + (size_t)chan * 256 + quad * 8;
            bias[i] = qkv_b[chan];
        }
        float4v acc[4][6];
#pragma unroll
        for (int mt = 0; mt < 4; ++mt)
#pragma unroll
            for (int i = 0; i < 6; ++i)
                acc[mt][i] = (float4v)0.0f;

#pragma unroll
        for (int kt = 0; kt < 8; ++kt) {
            const int ku = (kt >> 1) & 3;
            short8 a[4];
#pragma unroll
            for (int mt = 0; mt < 4; ++mt) {
                int row = mt * 16 + n16;
                a[mt] = *(const short8*)&S.xs[((kt * 49 + row) << 5) + ((quad ^ rs ^ ku) << 3)];
            }
#pragma unroll
            for (int i = 0; i < 6; ++i) {
                short8 bb = *(const short8*)(bp[i] + kt * 32);
#pragma unroll
                for (int mt = 0; mt < 4; ++mt)
                    acc[mt][i] = __builtin_amdgcn_mfma_f32_16x16x32_bf16(a[mt], bb, acc[mt][i], 0, 0, 0);
            }
        }

        // ---- epilogue: q,k sigma-permuted cols (2*n16, 2*n16+1) packed b32; vT scalar ----
#pragma unroll
        for (int mt = 0; mt < 4; ++mt)
#pragma unroll
            for (int reg = 0; reg < 4; ++reg) {
                int r = mt * 16 + quad * 4 + reg;
                if (r < NTOK) {
                    unsigned q0 = (unsigned short)f2bf((acc[mt][0][reg] + bias[0]) * scale);
                    unsigned q1 = (unsigned short)f2bf((acc[mt][1][reg] + bias[1]) * scale);
                    *(unsigned*)&W.r1.qk.q[r * 40 + 2 * n16] = q0 | (q1 << 16);
                    unsigned k0 = (unsigned short)f2bf(acc[mt][2][reg] + bias[2]);
                    unsigned k1 = (unsigned short)f2bf(acc[mt][3][reg] + bias[3]);
                    *(unsigned*)&W.r1.qk.k[r * 40 + 2 * n16] = k0 | (k1 << 16);
                    W.vT[n16 * 72 + r]        = f2bf(acc[mt][4][reg] + bias[4]);
                    W.vT[(16 + n16) * 72 + r] = f2bf(acc[mt][5][reg] + bias[5]);
                }
            }
        MEMFENCE;   // F1: epilogue writes before QK^T reads

        // ---- swapped QK^T: S^T = K . Q^T  (16 MFMA, K=32) ----
        short8 ak[4], bq[4];
#pragma unroll
        for (int t = 0; t < 4; ++t) {
            ak[t] = *(const short8*)&W.r1.qk.k[(t * 16 + n16) * 40 + quad * 8];
            bq[t] = *(const short8*)&W.r1.qk.q[(t * 16 + n16) * 40 + quad * 8];
        }
        float4v sa[4][4];   // [rt=key tile][ct=query tile]
#pragma unroll
        for (int rt = 0; rt < 4; ++rt)
#pragma unroll
            for (int ct = 0; ct < 4; ++ct)
                sa[rt][ct] = __builtin_amdgcn_mfma_f32_16x16x32_bf16(ak[rt], bq[ct], (float4v)0.0f, 0, 0, 0);

        // ---- + rel-bias + mask; keys >= 49 forced to -1e30 (kills stale NaN) ----
#pragma unroll
        for (int rt = 0; rt < 4; ++rt)
#pragma unroll
            for (int ct = 0; ct < 4; ++ct)
#pragma unroll
                for (int reg = 0; reg < 4; ++reg) {
                    float sv;
                    if (rt == 3 && !(quad == 0 && reg == 0)) sv = -1e30f;  // key >= 49
                    else {
                        int bidx = qv[ct] - kv[rt][reg] + 84;
                        bidx = (bidx > 168) ? 168 : bidx;
                        sv = sa[rt][ct][reg] + bf2f(S.btabt[h * 169 + bidx]) + mreg[rt][ct][reg];
                    }
                    sa[rt][ct][reg] = sv;
                }

        // ---- softmax over keys: lane-local 16 + 2 shuffles per query tile ----
#pragma unroll
        for (int ct = 0; ct < 4; ++ct) {
            float m0 = sa[0][ct][0];
#pragma unroll
            for (int rt = 0; rt < 4; ++rt)
#pragma unroll
                for (int reg = 0; reg < 4; ++reg)
                    m0 = fmaxf(m0, sa[rt][ct][reg]);
            m0 = fmaxf(m0, __shfl_xor(m0, 16));
            m0 = fmaxf(m0, __shfl_xor(m0, 32));
            float s0 = 0.f;
#pragma unroll
            for (int rt = 0; rt < 4; ++rt)
#pragma unroll
                for (int reg = 0; reg < 4; ++reg) {
                    float e = __expf(sa[rt][ct][reg] - m0);
                    sa[rt][ct][reg] = e;
                    s0 += e;
                }
            s0 += __shfl_xor(s0, 16);
            s0 += __shfl_xor(s0, 32);
            float inv = 1.0f / s0;
#pragma unroll
            for (int rt = 0; rt < 4; ++rt)
#pragma unroll
                for (int reg = 0; reg < 4; ++reg)
                    sa[rt][ct][reg] *= inv;
        }
        MEMFENCE;   // F2: QK^T reads before P writes (overlay)

        // ---- P^T -> LDS [q][k], swizzled, packed 4 keys per write ----
#pragma unroll
        for (int ct = 0; ct < 4; ++ct)
#pragma unroll
            for (int rt = 0; rt < 4; ++rt) {
                short4v pw;
                pw.x = f2bf(sa[rt][ct][0]); pw.y = f2bf(sa[rt][ct][1]);
                pw.z = f2bf(sa[rt][ct][2]); pw.w = f2bf(sa[rt][ct][3]);
                int su = (2 * rt + (quad >> 1)) ^ (n16 & 7);
                *(short4v*)&W.r1.p[((ct * 16 + n16) << 6) + (su << 3) + ((quad & 1) << 2)] = pw;
            }
        MEMFENCE;   // F3: P writes before PV reads

        // ---- PV: O^T[dim][q] = V^T . P^T  (16 MFMA over 2 key chunks) ----
        float4v oa[2][4];
#pragma unroll
        for (int mtv = 0; mtv < 2; ++mtv)
#pragma unroll
            for (int nt = 0; nt < 4; ++nt)
                oa[mtv][nt] = (float4v)0.0f;
#pragma unroll
        for (int kt2 = 0; kt2 < 2; ++kt2) {
            short8 av[2], bpv[4];
#pragma unroll
            for (int mtv = 0; mtv < 2; ++mtv)
                av[mtv] = *(const short8*)&W.vT[(mtv * 16 + n16) * 72 + kt2 * 32 + quad * 8];
#pragma unroll
            for (int nt = 0; nt < 4; ++nt) {
                int su = (kt2 * 4 + quad) ^ (n16 & 7);
                bpv[nt] = *(const short8*)&W.r1.p[((nt * 16 + n16) << 6) + (su << 3)];
            }
#pragma unroll
            for (int mtv = 0; mtv < 2; ++mtv)
#pragma unroll
                for (int nt = 0; nt < 4; ++nt)
                    oa[mtv][nt] = __builtin_amdgcn_mfma_f32_16x16x32_bf16(av[mtv], bpv[nt], oa[mtv][nt], 0, 0, 0);
        }
        MEMFENCE;   // F4: PV reads before o writes (overlay)

        // ---- o -> LDS, then coalesced 128B stores ----
#pragma unroll
        for (int mtv = 0; mtv < 2; ++mtv)
#pragma unroll
            for (int nt = 0; nt < 4; ++nt)
#pragma unroll
                for (int reg = 0; reg < 4; ++reg) {
                    int qvq = nt * 16 + n16;
                    if (qvq < NTOK)
                        W.r1.o[qvq * 36 + mtv * 16 + quad * 4 + reg] = oa[mtv][nt][reg];
                }
        MEMFENCE;   // F5: o writes before o reads
#pragma unroll
        for (int it = 0; it < 7; ++it) {
            int idx = it * 64 + lane;
            if (idx < NTOK * 8) {
                int tok = idx >> 3, c8 = idx & 7;
                float4v ov = *(const float4v*)&W.r1.o[tok * 36 + c8 * 4];
                *(float4v*)(out + xbase + (size_t)S.nsrc[tok] * CDIM + h * HDIM + c8 * 4) = ov;
            }
        }
        MEMFENCE;   // F6: o reads before next head's epilogue writes
    }
}

extern "C" void kernel_launch(void* const* d_in, const int* in_sizes, int n_in,
                              void* d_out, int out_size, void* d_ws, size_t ws_size,
                              hipStream_t stream) {
    const float* x      = (const float*)d_in[0];
    const float* mask   = (const float*)d_in[1];
    const float* qkv_w  = (const float*)d_in[2];
    const float* qkv_b  = (const float*)d_in[3];
    const float* btab   = (const float*)d_in[4];
    float* out = (float*)d_out;
    short* wb  = (short*)d_ws;                 // 768*256 bf16 = 384 KB

    cvt_w_kernel<<<dim3(192), dim3(256), 0, stream>>>(qkv_w, wb);
    swin_attn_kernel<<<dim3(4096), dim3(128), 0, stream>>>(
        x, mask, qkv_b, btab, wb, out);
}